// Round 2
// baseline (290.614 us; speedup 1.0000x reference)
//
#include <hip/hip_runtime.h>
#include <stdint.h>

// Problem constants
#define NMOL 4096
#define NATOMS (NMOL * 64)     // 262144
#define NF 124
#define NT 8
#define ROWV 125               // x_padded row stride in floats

// ws layout (bytes)
#define WS_TOTALS  0           // uint[8]
#define WS_CURSOR  32          // uint[8]
#define WS_DCONST  64          // float[8]
#define WS_HIST    128         // uint[256*8]
#define WS_TYPEBUF 8320        // uchar[NATOMS]
#define WS_LIST    270464      // uint[NATOMS]
#define WS_W1T     1319040     // ushort[8*64*128]  (f padded to 128, pad zeroed)
#define WS_W2T     1450112     // ushort[8*16*64]   (transposed [t][g][h])

typedef __attribute__((ext_vector_type(8))) short short8;
typedef __attribute__((ext_vector_type(4))) float floatx4;

__device__ __forceinline__ unsigned short f2bf(float f) {
    unsigned u = __builtin_bit_cast(unsigned, f);
    u += 0x7fffu + ((u >> 16) & 1u);
    return (unsigned short)(u >> 16);
}

// ---------------- K1: hist + typebuf + out-zero + weight prep ----------------
// blocks 0..255: atom histogram (per-block, no global atomics) + typebuf
// blocks 0..15 additionally zero out[]
// blocks 256,257: W1 -> W1T bf16 [t][h][f padded 128]
// block 258: W2 -> W2T bf16 [t][g][h]
__global__ __launch_bounds__(256) void k_hist(const float* __restrict__ x,
                                              const float* __restrict__ mask,
                                              const float* __restrict__ W1,
                                              const float* __restrict__ W2,
                                              unsigned* __restrict__ hist256,
                                              unsigned char* __restrict__ typebuf,
                                              unsigned short* __restrict__ W1T,
                                              unsigned short* __restrict__ W2T,
                                              float* __restrict__ out) {
    int tid = threadIdx.x;
    int b = blockIdx.x;
    if (b < 256) {
        __shared__ unsigned hist[NT];
        if (tid < NT) hist[tid] = 0u;
        __syncthreads();
        int base = b * 1024;
        for (int i = 0; i < 4; ++i) {
            int atom = base + i * 256 + tid;
            float tf = x[(size_t)atom * ROWV];
            float m  = mask[atom];
            unsigned char tb = 0xFF;
            if (m != 0.0f) { tb = (unsigned char)(int)tf; atomicAdd(&hist[tb], 1u); }
            typebuf[atom] = tb;
        }
        if (b < 16) out[b * 256 + tid] = 0.0f;
        __syncthreads();
        if (tid < NT) hist256[b * NT + tid] = hist[tid];
    } else if (b < 258) {
        for (int i = (b - 256) * 256 + tid; i < 8 * 64 * 128; i += 512) {
            int t = i >> 13, h = (i >> 7) & 63, f = i & 127;
            unsigned short v = 0;
            if (f < NF) v = f2bf(W1[(size_t)t * NF * 64 + f * 64 + h]);
            W1T[i] = v;
        }
    } else {
        for (int i = tid; i < 8 * 16 * 64; i += 256) {
            int t = i >> 10, g = (i >> 6) & 15, h = i & 63;
            W2T[i] = f2bf(W2[(size_t)t * 1024 + h * 16 + g]);
        }
    }
}

// ---------------- K2: hist reduce + fp32 constants + cursor init ----------------
__global__ __launch_bounds__(128) void k_setup(const float* __restrict__ b1,
                                               const float* __restrict__ W2,
                                               const float* __restrict__ b2,
                                               const float* __restrict__ W3,
                                               const float* __restrict__ b3,
                                               const unsigned* __restrict__ hist256,
                                               unsigned* totals, unsigned* cursor,
                                               float* dconst) {
    __shared__ float c[NT];
    __shared__ unsigned part[16][NT];
    __shared__ unsigned tot[NT];
    int tid = threadIdx.x;
    {   // exact fp32 constant c_t = MLP_t(0)
        int t = tid >> 4, g = tid & 15;
        float acc = b2[t * 16 + g];
        for (int h = 0; h < 64; ++h) {
            float h1 = b1[t * 64 + h];
            h1 = h1 > 0.f ? h1 : 0.f;
            acc += h1 * W2[(size_t)t * 1024 + h * 16 + g];
        }
        float h2 = acc > 0.f ? acc : 0.f;
        float v = h2 * W3[t * 16 + g];
        #pragma unroll
        for (int off = 1; off < 16; off <<= 1) v += __shfl_xor(v, off);
        if (g == 0) c[t] = v + b3[t];
    }
    {   // reduce 256-block histograms
        int t = tid & 7, chunk = tid >> 3;   // 16 chunks x 16 blocks
        unsigned s = 0;
        for (int j = 0; j < 16; ++j) s += hist256[(chunk * 16 + j) * NT + t];
        part[chunk][t] = s;
    }
    __syncthreads();
    if (tid < NT) {
        unsigned s = 0;
        for (int j = 0; j < 16; ++j) s += part[j][tid];
        tot[tid] = s;
        totals[tid] = s;
    }
    __syncthreads();
    if (tid == 0) {
        float T_ = 0.f;
        for (int i = 0; i < NT; ++i) T_ += c[i];
        unsigned run = 0;
        for (int i = 0; i < NT; ++i) {
            dconst[i] = T_ - c[i];
            cursor[i] = run;
            run += tot[i];
        }
    }
}

// ---------------- K3: counting-sort scatter ----------------
__global__ __launch_bounds__(256) void k_scatter(const unsigned char* __restrict__ typebuf,
                                                 unsigned* cursor, unsigned* list) {
    __shared__ unsigned hist[NT], basep[NT], cur[NT];
    int tid = threadIdx.x;
    if (tid < NT) { hist[tid] = 0u; cur[tid] = 0u; }
    __syncthreads();
    int base = blockIdx.x * 1024;
    unsigned char tb[4];
    for (int i = 0; i < 4; ++i) {
        tb[i] = typebuf[base + i * 256 + tid];
        if (tb[i] != 0xFF) atomicAdd(&hist[tb[i]], 1u);
    }
    __syncthreads();
    if (tid < NT && hist[tid]) basep[tid] = atomicAdd(&cursor[tid], hist[tid]);
    __syncthreads();
    for (int i = 0; i < 4; ++i) {
        if (tb[i] != 0xFF) {
            unsigned p = basep[tb[i]] + atomicAdd(&cur[tb[i]], 1u);
            list[p] = (unsigned)(base + i * 256 + tid);
        }
    }
}

// ---------------- K4: fused gather + 3-layer MLP (bf16 MFMA) ----------------
#define AS 136   // A row stride (bf16): odd in 16B units -> conflict-free b128 reads
#define HS 72    // h1 row stride (bf16)

__global__ __launch_bounds__(256, 3) void k_mlp(const float* __restrict__ x,
                                                const unsigned short* __restrict__ W1T,
                                                const float* __restrict__ b1,
                                                const unsigned short* __restrict__ W2T,
                                                const float* __restrict__ b2,
                                                const float* __restrict__ W3,
                                                const float* __restrict__ b3,
                                                const unsigned* __restrict__ totals,
                                                const float* __restrict__ dconst,
                                                const unsigned* __restrict__ list,
                                                float* __restrict__ out) {
    __shared__ unsigned short sA[128 * AS];   // feats tile; reused as h1[128][HS]
    __shared__ unsigned short sW[64 * AS];    // W1^T [h][f]; reused as W2^T [g][h]
    __shared__ unsigned sIds[128];

    // ---- locate (type, tile) ----
    unsigned g = blockIdx.x;
    unsigned cnt[NT], start[NT];
    {
        unsigned s = 0;
        for (int i = 0; i < NT; ++i) { cnt[i] = totals[i]; start[i] = s; s += cnt[i]; }
    }
    int t = -1; unsigned tile = 0;
    {
        unsigned tl = 0;
        for (int i = 0; i < NT; ++i) {
            unsigned nt_ = (cnt[i] + 127u) >> 7;
            if (t < 0 && g < tl + nt_) { t = i; tile = g - tl; }
            tl += nt_;
        }
    }
    if (t < 0) return;

    int valid = (int)cnt[t] - (int)(tile << 7);
    if (valid > 128) valid = 128;
    unsigned rowstart = start[t] + (tile << 7);

    int tid  = threadIdx.x;
    int wv   = tid >> 6;
    int lane = tid & 63;
    int quad = lane >> 4, l15 = lane & 15;

    // ---- ids for epilogue ----
    if (tid < 128) sIds[tid] = (tid < valid) ? list[rowstart + tid] : 0xFFFFFFFFu;

    // ---- stage W1T[t] -> sW (vectorized, pad already zeroed) ----
    {
        const unsigned short* w1g = W1T + (size_t)t * 8192;   // 64 x 128 shorts
        #pragma unroll
        for (int i = 0; i < 4; ++i) {
            int c = tid * 4 + i;            // 1024 chunks of 8 shorts
            int h = c >> 4, fp = (c & 15) * 8;
            *(short8*)(sW + h * AS + fp) = *(const short8*)(w1g + c * 8);
        }
    }

    // ---- coalesced gather: one wave stages one row at a time ----
    {
        unsigned ids = 0xFFFFFFFFu;
        if (lane < 32) {
            int r = wv * 32 + lane;
            if (r < valid) ids = list[rowstart + r];
        }
        int pos = lane < 62 ? 2 * lane : 124 + 2 * (lane - 62);
        #pragma unroll 8
        for (int r = 0; r < 32; ++r) {
            unsigned atom = (unsigned)__builtin_amdgcn_readlane((int)ids, r);
            unsigned short* dst = sA + (wv * 32 + r) * AS;
            unsigned pk = 0u;
            if (atom != 0xFFFFFFFFu) {
                const float* src = x + (size_t)atom * ROWV + 1;
                float a = 0.f, bb = 0.f;
                if (lane < 62) { a = src[2 * lane]; bb = src[2 * lane + 1]; }
                pk = (unsigned)f2bf(a) | ((unsigned)f2bf(bb) << 16);
            }
            *(unsigned*)(dst + pos) = pk;
        }
    }

    float b1v[4];
    #pragma unroll
    for (int n = 0; n < 4; ++n) b1v[n] = b1[t * 64 + n * 16 + l15];

    __syncthreads();

    // ---- layer 1: [128x128] x [128x64] ----
    floatx4 c1[2][4];
    #pragma unroll
    for (int m = 0; m < 2; ++m)
        #pragma unroll
        for (int n = 0; n < 4; ++n) c1[m][n] = (floatx4)0.f;

    int rowbase = wv * 32;
    #pragma unroll
    for (int ks = 0; ks < 4; ++ks) {
        int ko = ks * 32 + quad * 8;
        short8 a0 = *(const short8*)(sA + (rowbase + l15) * AS + ko);
        short8 a1 = *(const short8*)(sA + (rowbase + 16 + l15) * AS + ko);
        short8 bf[4];
        #pragma unroll
        for (int n = 0; n < 4; ++n)
            bf[n] = *(const short8*)(sW + (n * 16 + l15) * AS + ko);
        #pragma unroll
        for (int n = 0; n < 4; ++n) {
            c1[0][n] = __builtin_amdgcn_mfma_f32_16x16x32_bf16(a0, bf[n], c1[0][n], 0, 0, 0);
            c1[1][n] = __builtin_amdgcn_mfma_f32_16x16x32_bf16(a1, bf[n], c1[1][n], 0, 0, 0);
        }
    }

    __syncthreads();

    // ---- stage W2T[t] -> sW (vectorized) ----
    if (tid < 128) {
        const unsigned short* w2g = W2T + (size_t)t * 1024;   // 16 x 64 shorts
        int c = tid;                        // 128 chunks of 8
        int gg = c >> 3, hp = (c & 7) * 8;
        *(short8*)(sW + gg * HS + hp) = *(const short8*)(w2g + c * 8);
    }
    // ---- h1 = relu(c1 + b1) -> sA[row][HS] bf16 ----
    #pragma unroll
    for (int m = 0; m < 2; ++m)
        #pragma unroll
        for (int n = 0; n < 4; ++n) {
            int col = n * 16 + l15;
            #pragma unroll
            for (int r = 0; r < 4; ++r) {
                float v = c1[m][n][r] + b1v[n];
                v = v > 0.f ? v : 0.f;
                sA[(rowbase + m * 16 + quad * 4 + r) * HS + col] = f2bf(v);
            }
        }

    __syncthreads();

    // ---- layer 2: [128x64] x [64x16] ----
    floatx4 c2[2];
    c2[0] = (floatx4)0.f; c2[1] = (floatx4)0.f;
    #pragma unroll
    for (int ks = 0; ks < 2; ++ks) {
        int ko = ks * 32 + quad * 8;
        short8 a0 = *(const short8*)(sA + (rowbase + l15) * HS + ko);
        short8 a1 = *(const short8*)(sA + (rowbase + 16 + l15) * HS + ko);
        short8 bf = *(const short8*)(sW + l15 * HS + ko);
        c2[0] = __builtin_amdgcn_mfma_f32_16x16x32_bf16(a0, bf, c2[0], 0, 0, 0);
        c2[1] = __builtin_amdgcn_mfma_f32_16x16x32_bf16(a1, bf, c2[1], 0, 0, 0);
    }

    // ---- layer 3 + constant + atomic accumulate ----
    float b2v = b2[t * 16 + l15];
    float w3v = W3[t * 16 + l15];
    float tail = b3[t] + dconst[t];
    #pragma unroll
    for (int m = 0; m < 2; ++m) {
        float h2v[4];
        #pragma unroll
        for (int r = 0; r < 4; ++r) {
            float v = c2[m][r] + b2v;
            v = v > 0.f ? v : 0.f;
            h2v[r] = v * w3v;
        }
        #pragma unroll
        for (int off = 1; off < 16; off <<= 1)
            #pragma unroll
            for (int r = 0; r < 4; ++r) h2v[r] += __shfl_xor(h2v[r], off);
        if (l15 == 0) {
            #pragma unroll
            for (int r = 0; r < 4; ++r) {
                int trow = rowbase + m * 16 + quad * 4 + r;
                if (trow < valid) {
                    unsigned atom = sIds[trow];
                    atomicAdd(&out[atom >> 6], h2v[r] + tail);
                }
            }
        }
    }
}

extern "C" void kernel_launch(void* const* d_in, const int* in_sizes, int n_in,
                              void* d_out, int out_size, void* d_ws, size_t ws_size,
                              hipStream_t stream) {
    const float* x    = (const float*)d_in[0];
    const float* mask = (const float*)d_in[1];
    const float* W1   = (const float*)d_in[2];
    const float* b1   = (const float*)d_in[3];
    const float* W2   = (const float*)d_in[4];
    const float* b2   = (const float*)d_in[5];
    const float* W3   = (const float*)d_in[6];
    const float* b3   = (const float*)d_in[7];
    float* out = (float*)d_out;

    char* ws = (char*)d_ws;
    unsigned*       totals  = (unsigned*)(ws + WS_TOTALS);
    unsigned*       cursor  = (unsigned*)(ws + WS_CURSOR);
    float*          dconst  = (float*)(ws + WS_DCONST);
    unsigned*       hist256 = (unsigned*)(ws + WS_HIST);
    unsigned char*  typebuf = (unsigned char*)(ws + WS_TYPEBUF);
    unsigned*       list    = (unsigned*)(ws + WS_LIST);
    unsigned short* W1T     = (unsigned short*)(ws + WS_W1T);
    unsigned short* W2T     = (unsigned short*)(ws + WS_W2T);

    k_hist<<<259, 256, 0, stream>>>(x, mask, W1, W2, hist256, typebuf, W1T, W2T, out);
    k_setup<<<1, 128, 0, stream>>>(b1, W2, b2, W3, b3, hist256, totals, cursor, dconst);
    k_scatter<<<NATOMS / 1024, 256, 0, stream>>>(typebuf, cursor, list);
    k_mlp<<<2055, 256, 0, stream>>>(x, W1T, b1, W2T, b2, W3, b3,
                                    totals, dconst, list, out);
}

// Round 3
// 267.807 us; speedup vs baseline: 1.0852x; 1.0852x over previous
//
#include <hip/hip_runtime.h>
#include <stdint.h>

// Problem constants
#define NMOL 4096
#define NATOMS (NMOL * 64)
#define NF 124
#define NT 8
#define ROWV 125               // x_padded row stride in floats
#define CAP 65536              // rows per type segment (kept/type ~29.5K; 2.2x margin)

// ws layout (bytes)
#define WS_CURSOR   0          // uint[8]
#define WS_DCONST   64         // float[8]
#define WS_W2T      1024       // ushort[8*16*64]              (16 KB)
#define WS_W1S      18432      // ushort[8*64*128] swizzled    (128 KB)
#define WS_IDS      1048576    // uint[8*CAP]                  (2 MB)
#define WS_PACKED   4194304    // ushort[8*CAP*128] swizzled   (128 MB)

typedef __attribute__((ext_vector_type(8))) short short8;
typedef __attribute__((ext_vector_type(4))) float floatx4;
typedef __attribute__((ext_vector_type(4))) unsigned int uint4v;

__device__ __forceinline__ unsigned short f2bf(float f) {
    unsigned u = __builtin_bit_cast(unsigned, f);
    u += 0x7fffu + ((u >> 16) & 1u);
    return (unsigned short)(u >> 16);
}

__device__ __forceinline__ void ld_lds16(const void* g, void* lds) {
    // 16B-per-lane async global->LDS; LDS dest = uniform base + lane*16
    __builtin_amdgcn_global_load_lds(
        (const __attribute__((address_space(1))) unsigned int*)g,
        (__attribute__((address_space(3))) unsigned int*)lds, 16, 0, 0);
}

// ---------------- K1: setup (constants, cursors, out-zero, weight prep) ----------------
// b==0: dconst fp32 + cursor init; b 1..8: W1 -> W1S bf16 swizzled; b==9: W2 -> W2T;
// b 10..25: zero out[]
__global__ __launch_bounds__(256) void k_setup(const float* __restrict__ W1,
                                               const float* __restrict__ b1,
                                               const float* __restrict__ W2,
                                               const float* __restrict__ b2,
                                               const float* __restrict__ W3,
                                               const float* __restrict__ b3,
                                               unsigned* __restrict__ cursor,
                                               float* __restrict__ dconst,
                                               unsigned short* __restrict__ W1S,
                                               unsigned short* __restrict__ W2T,
                                               float* __restrict__ out) {
    int tid = threadIdx.x, b = blockIdx.x;
    if (b == 0) {
        __shared__ float c[NT];
        if (tid < 128) {           // exact fp32 constant c_t = MLP_t(0)
            int t = tid >> 4, g = tid & 15;
            float acc = b2[t * 16 + g];
            for (int h = 0; h < 64; ++h) {
                float h1 = b1[t * 64 + h];
                h1 = h1 > 0.f ? h1 : 0.f;
                acc += h1 * W2[(size_t)t * 1024 + h * 16 + g];
            }
            float h2 = acc > 0.f ? acc : 0.f;
            float v = h2 * W3[t * 16 + g];
            #pragma unroll
            for (int off = 1; off < 16; off <<= 1) v += __shfl_xor(v, off);
            if (g == 0) c[t] = v + b3[t];
        }
        if (tid < NT) cursor[tid] = (unsigned)(tid * CAP);
        __syncthreads();
        if (tid == 0) {
            float T_ = 0.f;
            for (int i = 0; i < NT; ++i) T_ += c[i];
            for (int i = 0; i < NT; ++i) dconst[i] = T_ - c[i];
        }
    } else if (b <= 8) {
        int t = b - 1;
        const float* w1g = W1 + (size_t)t * NF * 64;
        unsigned short* dst = W1S + (size_t)t * 8192;
        for (int id = tid; id < 1024; id += 256) {   // (h, chunk c) tasks
            int h = id >> 4, cc = id & 15;
            unsigned u[4];
            #pragma unroll
            for (int j = 0; j < 4; ++j) {
                int f0 = cc * 8 + 2 * j;
                unsigned short lo = (f0 < NF)     ? f2bf(w1g[f0 * 64 + h])       : (unsigned short)0;
                unsigned short hi = (f0 + 1 < NF) ? f2bf(w1g[(f0 + 1) * 64 + h]) : (unsigned short)0;
                u[j] = (unsigned)lo | ((unsigned)hi << 16);
            }
            int p = cc ^ (h & 15);
            *(uint4v*)(dst + h * 128 + p * 8) = (uint4v){u[0], u[1], u[2], u[3]};
        }
    } else if (b == 9) {
        for (int i = tid; i < 8 * 16 * 64; i += 256) {
            int t = i >> 10, g = (i >> 6) & 15, h = i & 63;
            W2T[i] = f2bf(W2[(size_t)t * 1024 + h * 16 + g]);
        }
    } else {
        out[(b - 10) * 256 + tid] = 0.0f;
    }
}

// ---------------- K2: streaming pack (coalesced read, sorted scatter write) ----------------
__global__ __launch_bounds__(256, 4) void k_pack(const float* __restrict__ x,
                                                 const float* __restrict__ mask,
                                                 unsigned* __restrict__ cursor,
                                                 unsigned* __restrict__ ids,
                                                 unsigned short* __restrict__ packed) {
    __shared__ __align__(16) float sRaw[64 * ROWV];   // 8000 floats = 32 KB
    __shared__ unsigned sHist[NT], sBase[NT];
    __shared__ int sDest[64];
    int tid = threadIdx.x, b = blockIdx.x;            // block = molecule b (64 atoms)
    if (tid < NT) sHist[tid] = 0u;
    {   // coalesced float4 staging of 64 consecutive rows
        const uint4v* xs = (const uint4v*)(x + (size_t)b * 64 * ROWV);
        uint4v* sr = (uint4v*)sRaw;
        for (int i = tid; i < 2000; i += 256) sr[i] = xs[i];
    }
    float m = 0.f;
    if (tid < 64) m = mask[b * 64 + tid];
    __syncthreads();
    int t = 0, rank = -1;
    bool kept = false;
    if (tid < 64) {
        t = (int)sRaw[tid * ROWV];                    // type from LDS, no strided global read
        kept = (m != 0.f);
        if (kept) rank = (int)atomicAdd(&sHist[t], 1u);
    }
    __syncthreads();
    if (tid < NT && sHist[tid]) sBase[tid] = atomicAdd(&cursor[tid], sHist[tid]);
    __syncthreads();
    if (tid < 64) {
        int d = kept ? (int)(sBase[t] + (unsigned)rank) : -1;
        sDest[tid] = d;
        if (kept) ids[d] = (unsigned)b;               // molecule id
    }
    __syncthreads();
    // write-out: 8 threads per row, 16 shorts (2 swizzled 16B chunks) each
    for (int s = tid; s < 512; s += 256) {
        int r = s >> 3, k = s & 7;
        int d = sDest[r];
        if (d < 0) continue;
        const float* src = sRaw + r * ROWV + 1;
        unsigned u[8];
        #pragma unroll
        for (int j = 0; j < 8; ++j) {
            int c0 = k * 16 + 2 * j;
            float a  = (c0 < NF)     ? src[c0]     : 0.f;
            float bb = (c0 + 1 < NF) ? src[c0 + 1] : 0.f;
            u[j] = (unsigned)f2bf(a) | ((unsigned)f2bf(bb) << 16);
        }
        int skey = d & 15;
        uint4v* drow = (uint4v*)(packed + (size_t)d * 128);
        drow[(2 * k) ^ skey]     = (uint4v){u[0], u[1], u[2], u[3]};
        drow[(2 * k + 1) ^ skey] = (uint4v){u[4], u[5], u[6], u[7]};
    }
}

// ---------------- K3: MFMA MLP over sorted packed tiles ----------------
#define HS 72   // h1 row stride (bf16)

__global__ __launch_bounds__(256, 3) void k_mlp(const unsigned short* __restrict__ packed,
                                                const unsigned short* __restrict__ W1S,
                                                const float* __restrict__ b1,
                                                const unsigned short* __restrict__ W2T,
                                                const float* __restrict__ b2,
                                                const float* __restrict__ W3,
                                                const float* __restrict__ b3,
                                                const unsigned* __restrict__ cursor,
                                                const float* __restrict__ dconst,
                                                const unsigned* __restrict__ ids,
                                                float* __restrict__ out) {
    __shared__ unsigned short sA[128 * 128];   // swizzled A tile; reused as h1[128][HS]
    __shared__ unsigned short sW[64 * 128];    // swizzled W1; reused as W2^T [g][HS]
    __shared__ unsigned sIds[128];

    int t = blockIdx.x >> 9;
    int tile = blockIdx.x & 511;
    int cnt = (int)(cursor[t] - (unsigned)(t * CAP));
    int valid = cnt - (tile << 7);
    if (valid <= 0) return;
    if (valid > 128) valid = 128;

    int tid  = threadIdx.x;
    int wv   = tid >> 6;
    int lane = tid & 63;
    int quad = lane >> 4, l15 = lane & 15;
    int rowstart = t * CAP + (tile << 7);

    // ---- async stage A tile (32 KB contiguous) + W1 (16 KB) ----
    {
        const char* aseg = (const char*)packed + (size_t)rowstart * 256;
        #pragma unroll
        for (int i = 0; i < 8; ++i) {
            int off = (wv * 8 + i) * 1024;
            ld_lds16(aseg + off + lane * 16, (char*)sA + off);
        }
        const char* wseg = (const char*)W1S + (size_t)t * 16384;
        #pragma unroll
        for (int i = 0; i < 4; ++i) {
            int off = (wv * 4 + i) * 1024;
            ld_lds16(wseg + off + lane * 16, (char*)sW + off);
        }
    }
    if (tid < 128) sIds[tid] = ids[rowstart + tid];   // garbage beyond valid: gated later

    float b1v[4];
    #pragma unroll
    for (int n = 0; n < 4; ++n) b1v[n] = b1[t * 64 + n * 16 + l15];

    __syncthreads();   // drains global_load_lds (vmcnt) + lds

    // ---- layer 1: [128x128] x [128x64], XOR-16 swizzled chunks ----
    floatx4 c1[2][4];
    #pragma unroll
    for (int m = 0; m < 2; ++m)
        #pragma unroll
        for (int n = 0; n < 4; ++n) c1[m][n] = (floatx4)0.f;

    int rowbase = wv * 32;
    #pragma unroll
    for (int ks = 0; ks < 4; ++ks) {
        int p = ((ks * 4 + quad) ^ l15) * 8;
        short8 a0 = *(const short8*)(sA + (rowbase + l15) * 128 + p);
        short8 a1 = *(const short8*)(sA + (rowbase + 16 + l15) * 128 + p);
        short8 bf[4];
        #pragma unroll
        for (int n = 0; n < 4; ++n)
            bf[n] = *(const short8*)(sW + (n * 16 + l15) * 128 + p);
        #pragma unroll
        for (int n = 0; n < 4; ++n) {
            c1[0][n] = __builtin_amdgcn_mfma_f32_16x16x32_bf16(a0, bf[n], c1[0][n], 0, 0, 0);
            c1[1][n] = __builtin_amdgcn_mfma_f32_16x16x32_bf16(a1, bf[n], c1[1][n], 0, 0, 0);
        }
    }

    __syncthreads();

    // ---- stage W2T[t] -> sW [g][HS] ----
    if (tid < 128) {
        const unsigned short* w2g = W2T + (size_t)t * 1024;
        int gg = tid >> 3, hp = (tid & 7) * 8;
        *(short8*)(sW + gg * HS + hp) = *(const short8*)(w2g + tid * 8);
    }
    // ---- h1 = relu(c1 + b1) -> sA[row][HS] bf16 ----
    #pragma unroll
    for (int m = 0; m < 2; ++m)
        #pragma unroll
        for (int n = 0; n < 4; ++n) {
            int col = n * 16 + l15;
            #pragma unroll
            for (int r = 0; r < 4; ++r) {
                float v = c1[m][n][r] + b1v[n];
                v = v > 0.f ? v : 0.f;
                sA[(rowbase + m * 16 + quad * 4 + r) * HS + col] = f2bf(v);
            }
        }

    __syncthreads();

    // ---- layer 2: [128x64] x [64x16] ----
    floatx4 c2[2];
    c2[0] = (floatx4)0.f; c2[1] = (floatx4)0.f;
    #pragma unroll
    for (int ks = 0; ks < 2; ++ks) {
        int ko = ks * 32 + quad * 8;
        short8 a0 = *(const short8*)(sA + (rowbase + l15) * HS + ko);
        short8 a1 = *(const short8*)(sA + (rowbase + 16 + l15) * HS + ko);
        short8 bf = *(const short8*)(sW + l15 * HS + ko);
        c2[0] = __builtin_amdgcn_mfma_f32_16x16x32_bf16(a0, bf, c2[0], 0, 0, 0);
        c2[1] = __builtin_amdgcn_mfma_f32_16x16x32_bf16(a1, bf, c2[1], 0, 0, 0);
    }

    // ---- layer 3 + constant + atomic accumulate ----
    float b2v = b2[t * 16 + l15];
    float w3v = W3[t * 16 + l15];
    float tail = b3[t] + dconst[t];
    #pragma unroll
    for (int m = 0; m < 2; ++m) {
        float h2v[4];
        #pragma unroll
        for (int r = 0; r < 4; ++r) {
            float v = c2[m][r] + b2v;
            v = v > 0.f ? v : 0.f;
            h2v[r] = v * w3v;
        }
        #pragma unroll
        for (int off = 1; off < 16; off <<= 1)
            #pragma unroll
            for (int r = 0; r < 4; ++r) h2v[r] += __shfl_xor(h2v[r], off);
        if (l15 == 0) {
            #pragma unroll
            for (int r = 0; r < 4; ++r) {
                int trow = rowbase + m * 16 + quad * 4 + r;
                if (trow < valid) {
                    atomicAdd(&out[sIds[trow]], h2v[r] + tail);
                }
            }
        }
    }
}

extern "C" void kernel_launch(void* const* d_in, const int* in_sizes, int n_in,
                              void* d_out, int out_size, void* d_ws, size_t ws_size,
                              hipStream_t stream) {
    const float* x    = (const float*)d_in[0];
    const float* mask = (const float*)d_in[1];
    const float* W1   = (const float*)d_in[2];
    const float* b1   = (const float*)d_in[3];
    const float* W2   = (const float*)d_in[4];
    const float* b2   = (const float*)d_in[5];
    const float* W3   = (const float*)d_in[6];
    const float* b3   = (const float*)d_in[7];
    float* out = (float*)d_out;

    char* ws = (char*)d_ws;
    unsigned*       cursor = (unsigned*)(ws + WS_CURSOR);
    float*          dconst = (float*)(ws + WS_DCONST);
    unsigned short* W2T    = (unsigned short*)(ws + WS_W2T);
    unsigned short* W1S    = (unsigned short*)(ws + WS_W1S);
    unsigned*       ids    = (unsigned*)(ws + WS_IDS);
    unsigned short* packed = (unsigned short*)(ws + WS_PACKED);

    k_setup<<<26, 256, 0, stream>>>(W1, b1, W2, b2, W3, b3, cursor, dconst, W1S, W2T, out);
    k_pack<<<NMOL, 256, 0, stream>>>(x, mask, cursor, ids, packed);
    k_mlp<<<NT * (CAP / 128), 256, 0, stream>>>(packed, W1S, b1, W2T, b2, W3, b3,
                                                cursor, dconst, ids, out);
}